// Round 24
// baseline (400.003 us; speedup 1.0000x reference)
//
#include <hip/hip_runtime.h>
#include <stdint.h>

#define BDIM 32
#define CDIM 32
#define LDIM 1024
#define VDIM 4096
#define BCL (BDIM*CDIM*LDIM)

typedef _Float16 f16x8 __attribute__((ext_vector_type(8)));
typedef float f32x4 __attribute__((ext_vector_type(4)));

#define PIN_V(x) asm volatile("" : "+v"(x))

__device__ __forceinline__ unsigned long long pack_key(float bd, int bv) {
    unsigned u = __float_as_uint(bd);
    u = (u & 0x80000000u) ? ~u : (u | 0x80000000u);
    return ((unsigned long long)u << 32) | (unsigned)bv;
}

// ---------------------------------------------------------------- init (fallback path only)
__global__ void init_kernel(const float* __restrict__ f, const float* __restrict__ emb,
                            float* __restrict__ f_rest,
                            float* __restrict__ e_sq, float* __restrict__ loss_acc,
                            unsigned* __restrict__ done_ctr,
                            unsigned long long* __restrict__ keys, int nkeys) {
    int i = blockIdx.x * blockDim.x + threadIdx.x;
    if (i < BCL) f_rest[i] = f[i];
    if (i < VDIM) {
        const float* e = emb + (size_t)i * CDIM;
        float s = 0.f;
#pragma unroll
        for (int k = 0; k < 32; ++k) { float v = e[k]; s = fmaf(v, v, s); }
        e_sq[i] = s;
    }
    if (i < nkeys) keys[i] = ~0ull;
    if (i == 0) { *loss_acc = 0.f; *done_ctr = 0u; }
}

// ---------------------------------------------------------------- VQ si0/si1: block-per-query
// One block per query, direct keys[q] store (sole writer -> no key init, no atomics).
// si0 reads f directly; si0's launch carries 16 prep blocks (e_sq + (-2)-folded fp16
// e-split + acc zero). Dot chain c=0..31, strict <, ascending v (bit-identical).
__global__ __launch_bounds__(256) void vq_small(
    const float* __restrict__ src, const float* __restrict__ emb,
    _Float16* __restrict__ eh, _Float16* __restrict__ el, float* __restrict__ e_sq,
    unsigned long long* __restrict__ keys,
    float* __restrict__ loss_acc, unsigned* __restrict__ done_ctr,
    int lpl, int s, int NQ)
{
    const int bid = blockIdx.x, t = threadIdx.x;
    if (bid >= NQ) {                      // prep block (grid > NQ only at si0)
        if (bid == NQ && t == 0) { *loss_acc = 0.f; *done_ctr = 0u; }
        int i = (bid - NQ) * 256 + t;
        if (i < VDIM) {
            const float* e = emb + (size_t)i * 32;
            float ssum = 0.f;
#pragma unroll
            for (int k = 0; k < 32; ++k) {
                float v = e[k];
                ssum = fmaf(v, v, ssum);
                _Float16 h = (_Float16)v;
                float r = v - (float)h;
                eh[(size_t)i*32 + k] = (_Float16)(-2.0f) * h;
                el[(size_t)i*32 + k] = (_Float16)(-2.0f) * (_Float16)r;
            }
            e_sq[i] = ssum;
        }
        return;
    }

    const int pl = 1 << lpl;
    const int q = bid;
    const int b = q >> lpl, j = q & (pl - 1);
    const int col = j * s + (s >> 1) - 1;
    const float* p = src + b * (CDIM * LDIM) + col;
    float z[32];
#pragma unroll
    for (int c = 0; c < 32; ++c) z[c] = 0.5f * (p[c * LDIM] + p[c * LDIM + 1]);

    float bd = 3.4e38f; int bv = 0;
    const int vs = t * 16;
    for (int v = vs; v < vs + 16; ++v) {
        const float* e = emb + (size_t)v * 32;
        float ev[32];
#pragma unroll
        for (int c = 0; c < 32; ++c) ev[c] = e[c];
        float es = 0.f;
#pragma unroll
        for (int c = 0; c < 32; ++c) es = fmaf(ev[c], ev[c], es);
        float a = z[0] * ev[0];
#pragma unroll
        for (int c = 1; c < 32; ++c) a = fmaf(z[c], ev[c], a);
        float d = fmaf(a, -2.0f, es);
        if (d < bd) { bd = d; bv = v; }
    }

    unsigned long long key = pack_key(bd, bv);
#pragma unroll
    for (int m = 1; m < 64; m <<= 1) {
        unsigned long long o = __shfl_xor(key, m, 64); if (o < key) key = o;
    }
    __shared__ unsigned long long redk[4];
    if ((t & 63) == 0) redk[t >> 6] = key;
    __syncthreads();
    if (t == 0) {
        unsigned long long kk = redk[0];
#pragma unroll
        for (int m = 1; m < 4; ++m) if (redk[m] < kk) kk = redk[m];
        keys[q] = kk;
    }
}

// ---------------------------------------------------------------- VQ argmin via MFMA (si>=2)
// r19-verified: vsub loop, XOR swizzle (conflict-free), 3-MFMA split, esq preload,
// per-lane argmin + shfl_xor reduce, strict < ascending v tie-break.
__global__ __launch_bounds__(256) void vq_mfma(
    const _Float16* __restrict__ z_hi, const _Float16* __restrict__ z_lo,
    const _Float16* __restrict__ e_hi, const _Float16* __restrict__ e_lo,
    const float* __restrict__ e_sq, unsigned long long* __restrict__ keys,
    int NQ, int VC, int vchunks, int vsub)
{
    const int t = threadIdx.x;
    const int lane = t & 63;
    const int w = t >> 6;
    const int qg = blockIdx.x / vchunks;
    const int vc = blockIdx.x % vchunks;
    const int vb0 = vc * (vsub * VC);

    __shared__ __align__(16) _Float16 eh_ls[256*32];
    __shared__ __align__(16) _Float16 el_ls[256*32];
    __shared__ float esq_ls[256];

    const int fr = lane & 15;
    const int kq = lane >> 4;
    const int qbase = qg*256 + w*64;
    f16x8 ah[4], al[4];
#pragma unroll
    for (int tq = 0; tq < 4; ++tq) {
        int q = qbase + tq*16 + fr;
        ah[tq] = *(const f16x8*)(z_hi + (size_t)q*32 + kq*8);
        al[tq] = *(const f16x8*)(z_lo + (size_t)q*32 + kq*8);
    }

    float bd[4][4]; int bv[4][4];
#pragma unroll
    for (int tq = 0; tq < 4; ++tq)
#pragma unroll
        for (int i = 0; i < 4; ++i) { bd[tq][i] = 3.4e38f; bv[tq][i] = 0; }

    for (int sub = 0; sub < vsub; ++sub) {
        const int vb = vb0 + sub * VC;
        {
            const float4* sH = (const float4*)(e_hi + (size_t)vb*32);
            const float4* sL = (const float4*)(e_lo + (size_t)vb*32);
            float4* dH = (float4*)eh_ls; float4* dL = (float4*)el_ls;
            int n4 = VC * 4;
            for (int x = t; x < n4; x += 256) {
                int row = x >> 2, c = x & 3;
                int ds = row*4 + (c ^ ((row >> 1) & 3));
                dH[ds] = sH[x]; dL[ds] = sL[x];
            }
            for (int v = t; v < VC; v += 256) esq_ls[v] = e_sq[vb + v];
        }
        __syncthreads();

        for (int vt = 0; vt < VC; vt += 16) {
            const int row = vt + fr;
            const int koff = (kq ^ ((row >> 1) & 3)) * 8;
            const f16x8 bh = *(const f16x8*)(eh_ls + (size_t)row*32 + koff);
            const f16x8 bl = *(const f16x8*)(el_ls + (size_t)row*32 + koff);
            float es = esq_ls[row];
            int vg = vb + row;
#pragma unroll
            for (int tq = 0; tq < 4; ++tq) {
                f32x4 acc = {es, es, es, es};
                acc = __builtin_amdgcn_mfma_f32_16x16x32_f16(ah[tq], bh, acc, 0,0,0);
                acc = __builtin_amdgcn_mfma_f32_16x16x32_f16(ah[tq], bl, acc, 0,0,0);
                acc = __builtin_amdgcn_mfma_f32_16x16x32_f16(al[tq], bh, acc, 0,0,0);
#pragma unroll
                for (int i = 0; i < 4; ++i)
                    if (acc[i] < bd[tq][i]) { bd[tq][i] = acc[i]; bv[tq][i] = vg; }
            }
        }
        __syncthreads();
    }

#pragma unroll
    for (int tq = 0; tq < 4; ++tq) {
#pragma unroll
        for (int i = 0; i < 4; ++i) {
            unsigned long long k = pack_key(bd[tq][i], bv[tq][i]);
#pragma unroll
            for (int m = 1; m < 16; m <<= 1) {
                unsigned long long o = __shfl_xor(k, m, 64); if (o < k) k = o;
            }
            if (fr == 0) atomicMin(&keys[qbase + tq*16 + kq*4 + i], k);
        }
    }
}

// ---------------------------------------------------------------- fused gather+upsample+phi+update+loss
// ROUND-24 (r23 counters: fuse 43us, occupancy 13.7% at grid 512 = 2 blocks/CU, HBM 650GB/s):
//  (a) f_hat ELIMINATED from si0..si4 via the invariant f_hat == f - f_rest:
//      df = fh - f = -fr  =>  lsum += fr*fr (exact at si0; ~1e-7 reorder elsewhere).
//      si5 (to_hat) writes f_hat = f - fr once; f_rest not written at si5.
//      ~Halves fuse HBM traffic.
//  (b) CHUNK templated: 16 (grid 64x32 = 2048 blocks = 8/CU) everywhere except si1,
//      whose z-write needs CHUNK >= s_next=64 (keeps verified 64-chunk).
//  Gather staged via LDS (v0,v1,wg) + all-thread lerp; conv unroll 2 (r23-verified).
template<int CHUNK>
__global__ __launch_bounds__(256) void fuse_kernel(
    const float* __restrict__ f, const float* __restrict__ emb,
    const unsigned long long* __restrict__ keys,
    unsigned long long* __restrict__ keys_next, int nq_next,
    _Float16* __restrict__ zh_next, _Float16* __restrict__ zl_next, int s_next,
    const float* __restrict__ w, const float* __restrict__ bias,
    float* __restrict__ f_rest, float* __restrict__ f_hat,
    float* __restrict__ loss_acc, unsigned* __restrict__ done_ctr,
    float* __restrict__ out_loss, int pl, int from_f, int to_hat)
{
    constexpr int COLS = CHUNK + 2;
    constexpr int STR  = CHUNK + 4;
    constexpr int LPT  = CHUNK / 8;      // L-elements per thread
    const int t  = threadIdx.x;
    const int b  = blockIdx.y;
    const int l0 = blockIdx.x * CHUNK;

    if (keys_next) {
        int x = (b * gridDim.x + blockIdx.x) * 256 + t;
        if (x < nq_next) keys_next[x] = ~0ull;
    }

    __shared__ float w_s[3072];
    __shared__ float b_s[32];
    __shared__ float hs[32 * STR];
    __shared__ float red[4];
    __shared__ int   v0s[COLS], v1s[COLS];
    __shared__ float wgs[COLS];

    for (int x = t; x < 3072; x += 256) w_s[x] = w[x];
    if (t < 32) b_s[t] = bias[t];

    if (t < COLS) {
        int l = l0 - 1 + t;
        if (l < 0 || l >= LDIM) {
            v0s[t] = -1;
        } else {
            int lo, hi; float wg;
            if (pl == LDIM) { lo = l; hi = l; wg = 0.f; }
            else {
                float pos = (l + 0.5f) * ((float)pl / 1024.0f) - 0.5f;
                pos = fminf(fmaxf(pos, 0.f), (float)(pl - 1));
                lo = (int)floorf(pos);
                hi = min(lo + 1, pl - 1);
                wg = pos - (float)lo;
            }
            v0s[t] = (int)(keys[b * pl + lo] & 0xFFFFFFFFull);
            v1s[t] = (int)(keys[b * pl + hi] & 0xFFFFFFFFull);
            wgs[t] = wg;
        }
    }
    __syncthreads();

    // parallel gather: COLS x 8 quads over 256 threads
    for (int x = t; x < COLS * 8; x += 256) {
        int cx = x >> 3, i4 = x & 7;
        int v0 = v0s[cx];
        if (v0 < 0) {
            hs[(i4*4+0) * STR + cx] = 0.f;
            hs[(i4*4+1) * STR + cx] = 0.f;
            hs[(i4*4+2) * STR + cx] = 0.f;
            hs[(i4*4+3) * STR + cx] = 0.f;
        } else {
            float4 a = ((const float4*)(emb + (size_t)v0 * 32))[i4];
            float4 c = ((const float4*)(emb + (size_t)v1s[cx] * 32))[i4];
            float wg = wgs[cx], om = 1.0f - wg;
            hs[(i4*4+0) * STR + cx] = a.x * om + c.x * wg;
            hs[(i4*4+1) * STR + cx] = a.y * om + c.y * wg;
            hs[(i4*4+2) * STR + cx] = a.z * om + c.z * wg;
            hs[(i4*4+3) * STR + cx] = a.w * om + c.w * wg;
        }
    }
    __syncthreads();

    const int o  = t >> 3;
    const int lg = t & 7;
    const float* wrow = &w_s[o * 96];
    float acc[LPT];
#pragma unroll
    for (int u = 0; u < LPT; ++u) acc[u] = 0.f;
    const int hbase = lg * LPT;

#pragma unroll 2
    for (int i = 0; i < 32; ++i) {
        float w0 = wrow[i * 3 + 0], w1 = wrow[i * 3 + 1], w2 = wrow[i * 3 + 2];
        const float* hrow = &hs[i * STR + hbase];
        float hw[LPT + 2];
#pragma unroll
        for (int x = 0; x < LPT + 2; ++x) hw[x] = hrow[x];
#pragma unroll
        for (int u = 0; u < LPT; ++u) {
            acc[u] = fmaf(w0, hw[u], acc[u]);
            acc[u] = fmaf(w1, hw[u + 1], acc[u]);
            acc[u] = fmaf(w2, hw[u + 2], acc[u]);
        }
    }

    float lsum = 0.f;
    float frv[LPT];
    const int gbase = (b * 32 + o) * LDIM + l0 + lg * LPT;
#pragma unroll
    for (int u = 0; u < LPT; ++u) {
        float hval = hs[o * STR + lg * LPT + 1 + u];
        float y = acc[u] + b_s[o];
        float ph = 0.5f * hval + 0.5f * y;
        int gi = gbase + u;
        float fr = (from_f ? f[gi] : f_rest[gi]) - ph;
        if (to_hat) f_hat[gi] = f[gi] - fr;
        else        f_rest[gi] = fr;
        frv[u] = fr;
        lsum = fmaf(fr, fr, lsum);      // df = fh - f = -fr
    }

    if (zh_next) {
        __syncthreads();
#pragma unroll
        for (int u = 0; u < LPT; ++u) hs[o * STR + lg * LPT + u] = frv[u];
        __syncthreads();
        int npos = CHUNK / s_next;
        int qn_base = b * (LDIM / s_next) + l0 / s_next;
        for (int v = t; v < npos * 32; v += 256) {
            int jl = v >> 5, c = v & 31;
            float zv;
            if (s_next == 1) zv = hs[c * STR + jl];
            else {
                int cl = jl * s_next + (s_next >> 1) - 1;
                zv = 0.5f * (hs[c * STR + cl] + hs[c * STR + cl + 1]);
            }
            _Float16 h = (_Float16)zv;
            float r = zv - (float)h;
            size_t zi = (size_t)(qn_base + jl) * 32 + c;
            zh_next[zi] = h;
            zl_next[zi] = (_Float16)r;
        }
    }

#pragma unroll
    for (int off = 32; off > 0; off >>= 1) lsum += __shfl_down(lsum, off, 64);
    if ((t & 63) == 0) red[t >> 6] = lsum;
    __syncthreads();
    if (t == 0) {
        atomicAdd(loss_acc, red[0] + red[1] + red[2] + red[3]);
        if (out_loss) {
            __threadfence();
            unsigned old = atomicAdd(done_ctr, 1u);
            if (old == (unsigned)(gridDim.x * gridDim.y - 1)) {
                float lv = atomicAdd(loss_acc, 0.0f);
                *out_loss = lv * (1.25f / (6.0f * (float)BCL));
            }
        }
    }
}

// ---------------------------------------------------------------- launch
extern "C" void kernel_launch(void* const* d_in, const int* in_sizes, int n_in,
                              void* d_out, int out_size, void* d_ws, size_t ws_size,
                              hipStream_t stream)
{
    const float* f    = (const float*)d_in[0];
    const float* emb  = (const float*)d_in[1];
    const float* phiw = (const float*)d_in[2];
    const float* phib = (const float*)d_in[3];

    float* f_hat    = (float*)d_out;
    float* out_loss = f_hat + BCL;

    const int pls[6]   = {1, 4, 16, 64, 256, 1024};
    const int lpls[6]  = {0, 2, 4, 6, 8, 10};
    const int vchm[6]  = {0, 0, 64, 16, 8, 4};
    const int vsbm[6]  = {0, 0, 1, 1, 2, 4};
    const int pidx[6]  = {0, 0, 1, 2, 3, 3};
    const int snx[6]   = {256, 64, 16, 4, 1, 0};

    char* ws = (char*)d_ws;
    float* f_rest = (float*)ws;

    size_t base = (size_t)BCL * 4;
    size_t off = base;
    unsigned long long* keysA = (unsigned long long*)(ws + off);
    unsigned long long* keysB = keysA + 32768;
    off += (size_t)65536 * 8;
    _Float16* z_hi = (_Float16*)(ws + off); off += (size_t)32768 * 32 * 2;
    _Float16* z_lo = (_Float16*)(ws + off); off += (size_t)32768 * 32 * 2;
    _Float16* e_hi = (_Float16*)(ws + off); off += (size_t)VDIM * 32 * 2;
    _Float16* e_lo = (_Float16*)(ws + off); off += (size_t)VDIM * 32 * 2;
    size_t need_mf = off + (size_t)VDIM * 4 + 64;
    bool mf = ws_size >= need_mf;

    if (mf) {
        float* e_sq        = (float*)(ws + off);
        float* loss_acc    = e_sq + VDIM;
        unsigned* done_ctr = (unsigned*)(loss_acc + 1);

        for (int si = 0; si < 6; ++si) {
            int pl = pls[si], s = LDIM / pl, NQ = BDIM * pl;
            unsigned long long* k  = (si & 1) ? keysB : keysA;
            unsigned long long* kn = (si >= 1 && si < 5) ? ((si & 1) ? keysA : keysB) : nullptr;
            int nq_next = (si < 5) ? BDIM * pls[si + 1] : 0;

            if (si <= 1) {
                int grid = NQ + (si == 0 ? 16 : 0);
                vq_small<<<dim3(grid), 256, 0, stream>>>(
                    (si == 0) ? f : f_rest, emb, e_hi, e_lo, e_sq, k,
                    loss_acc, done_ctr, lpls[si], s, NQ);
            } else {
                int vcm = vchm[si], vsb = vsbm[si];
                int VC = VDIM / (vcm * vsb);
                vq_mfma<<<dim3((NQ / 256) * vcm), 256, 0, stream>>>(
                    z_hi, z_lo, e_hi, e_lo, e_sq, k, NQ, VC, vcm, vsb);
            }

            bool zw = (si >= 1 && si <= 4);
            _Float16* zh = zw ? z_hi : nullptr;
            _Float16* zl = zw ? z_lo : nullptr;
            const float* wsi = phiw + (size_t)pidx[si] * 3072;
            const float* bsi = phib + (size_t)pidx[si] * 32;
            int from_f = (si == 0) ? 1 : 0;
            int to_hat = (si == 5) ? 1 : 0;
            float* ol = (si == 5) ? out_loss : nullptr;

            if (si == 1) {
                fuse_kernel<64><<<dim3(16, 32), 256, 0, stream>>>(
                    f, emb, k, kn, nq_next, zh, zl, snx[si], wsi, bsi,
                    f_rest, f_hat, loss_acc, done_ctr, ol, pl, from_f, to_hat);
            } else {
                fuse_kernel<16><<<dim3(64, 32), 256, 0, stream>>>(
                    f, emb, k, kn, nq_next, zh, zl, snx[si], wsi, bsi,
                    f_rest, f_hat, loss_acc, done_ctr, ol, pl, from_f, to_hat);
            }
        }
        return;
    }

    // ---- small-ws fallback: scan pipeline (correctness-first, uses same fuse semantics)
    {
        off = base;
        size_t need_pp = base + (size_t)65536 * 8 + (size_t)VDIM * 4 + 64;
        bool pp = ws_size >= need_pp;
        keysB = pp ? keysA + 32768 : keysA;
        off += pp ? (size_t)65536 * 8 : (size_t)32768 * 8;
        float* e_sq        = (float*)(ws + off);
        float* loss_acc    = e_sq + VDIM;
        unsigned* done_ctr = (unsigned*)(loss_acc + 1);

        init_kernel<<<dim3((BCL + 255) / 256), 256, 0, stream>>>(
            f, emb, f_rest, e_sq, loss_acc, done_ctr, keysA, 32768);

        for (int si = 0; si < 6; ++si) {
            int pl = pls[si], s = LDIM / pl, NQ = BDIM * pl;
            unsigned long long* k  = (si & 1) ? keysB : keysA;
            unsigned long long* kn = (si < 5 && pp) ? ((si & 1) ? keysA : keysB) : nullptr;
            int nq_next = (si < 5) ? BDIM * pls[si + 1] : 0;
            if (!pp && si > 0) hipMemsetAsync(k, 0xFF, (size_t)NQ * 8, stream);
            // block-per-query scan works for every scale (NQ blocks, 16 codes/thread)
            vq_small<<<dim3(NQ), 256, 0, stream>>>(
                (si == 0) ? f : f_rest, emb, nullptr, nullptr, e_sq, k,
                loss_acc, done_ctr, lpls[si], s, NQ);
            fuse_kernel<64><<<dim3(16, 32), 256, 0, stream>>>(
                f, emb, k, kn, nq_next, nullptr, nullptr, snx[si],
                phiw + (size_t)pidx[si] * 3072, phib + (size_t)pidx[si] * 32,
                f_rest, f_hat, loss_acc, done_ctr,
                (si == 5) ? out_loss : nullptr, pl, (si == 0) ? 1 : 0, (si == 5) ? 1 : 0);
        }
    }
}

// Round 25
// 306.759 us; speedup vs baseline: 1.3040x; 1.3040x over previous
//
#include <hip/hip_runtime.h>
#include <stdint.h>

#define BDIM 32
#define CDIM 32
#define LDIM 1024
#define VDIM 4096
#define BCL (BDIM*CDIM*LDIM)

typedef _Float16 f16x8 __attribute__((ext_vector_type(8)));
typedef float f32x4 __attribute__((ext_vector_type(4)));

#define PIN_V(x) asm volatile("" : "+v"(x))

__device__ __forceinline__ unsigned long long pack_key(float bd, int bv) {
    unsigned u = __float_as_uint(bd);
    u = (u & 0x80000000u) ? ~u : (u | 0x80000000u);
    return ((unsigned long long)u << 32) | (unsigned)bv;
}

// ---------------------------------------------------------------- init (fallback path only)
__global__ void init_kernel(const float* __restrict__ f, const float* __restrict__ emb,
                            float* __restrict__ f_rest,
                            float* __restrict__ e_sq, float* __restrict__ loss_acc,
                            unsigned* __restrict__ done_ctr,
                            unsigned long long* __restrict__ keys, int nkeys) {
    int i = blockIdx.x * blockDim.x + threadIdx.x;
    if (i < BCL) f_rest[i] = f[i];
    if (i < VDIM) {
        const float* e = emb + (size_t)i * CDIM;
        float s = 0.f;
#pragma unroll
        for (int k = 0; k < 32; ++k) { float v = e[k]; s = fmaf(v, v, s); }
        e_sq[i] = s;
    }
    if (i < nkeys) keys[i] = ~0ull;
    if (i == 0) { *loss_acc = 0.f; *done_ctr = 0u; }
}

// ---------------------------------------------------------------- VQ si0/si1: block-per-query
// One block per query, direct keys[q] store (sole writer -> no key init, no atomics).
// si0 reads f directly; si0's launch carries 16 prep blocks (e_sq + (-2)-folded fp16
// e-split + acc zero). Dot chain c=0..31, strict <, ascending v (bit-identical).
__global__ __launch_bounds__(256) void vq_small(
    const float* __restrict__ src, const float* __restrict__ emb,
    _Float16* __restrict__ eh, _Float16* __restrict__ el, float* __restrict__ e_sq,
    unsigned long long* __restrict__ keys,
    float* __restrict__ loss_acc, unsigned* __restrict__ done_ctr,
    int lpl, int s, int NQ)
{
    const int bid = blockIdx.x, t = threadIdx.x;
    if (bid >= NQ) {                      // prep block (grid > NQ only at si0)
        if (bid == NQ && t == 0) { *loss_acc = 0.f; *done_ctr = 0u; }
        int i = (bid - NQ) * 256 + t;
        if (i < VDIM) {
            const float* e = emb + (size_t)i * 32;
            float ssum = 0.f;
#pragma unroll
            for (int k = 0; k < 32; ++k) {
                float v = e[k];
                ssum = fmaf(v, v, ssum);
                _Float16 h = (_Float16)v;
                float r = v - (float)h;
                eh[(size_t)i*32 + k] = (_Float16)(-2.0f) * h;
                el[(size_t)i*32 + k] = (_Float16)(-2.0f) * (_Float16)r;
            }
            e_sq[i] = ssum;
        }
        return;
    }

    const int pl = 1 << lpl;
    const int q = bid;
    const int b = q >> lpl, j = q & (pl - 1);
    const int col = j * s + (s >> 1) - 1;
    const float* p = src + b * (CDIM * LDIM) + col;
    float z[32];
#pragma unroll
    for (int c = 0; c < 32; ++c) z[c] = 0.5f * (p[c * LDIM] + p[c * LDIM + 1]);

    float bd = 3.4e38f; int bv = 0;
    const int vs = t * 16;
    for (int v = vs; v < vs + 16; ++v) {
        const float* e = emb + (size_t)v * 32;
        float ev[32];
#pragma unroll
        for (int c = 0; c < 32; ++c) ev[c] = e[c];
        float es = 0.f;
#pragma unroll
        for (int c = 0; c < 32; ++c) es = fmaf(ev[c], ev[c], es);
        float a = z[0] * ev[0];
#pragma unroll
        for (int c = 1; c < 32; ++c) a = fmaf(z[c], ev[c], a);
        float d = fmaf(a, -2.0f, es);
        if (d < bd) { bd = d; bv = v; }
    }

    unsigned long long key = pack_key(bd, bv);
#pragma unroll
    for (int m = 1; m < 64; m <<= 1) {
        unsigned long long o = __shfl_xor(key, m, 64); if (o < key) key = o;
    }
    __shared__ unsigned long long redk[4];
    if ((t & 63) == 0) redk[t >> 6] = key;
    __syncthreads();
    if (t == 0) {
        unsigned long long kk = redk[0];
#pragma unroll
        for (int m = 1; m < 4; ++m) if (redk[m] < kk) kk = redk[m];
        keys[q] = kk;
    }
}

// ---------------------------------------------------------------- VQ argmin via MFMA (si>=2)
// r19-verified: vsub loop, XOR swizzle (conflict-free), 3-MFMA split, esq preload,
// per-lane argmin + shfl_xor reduce, strict < ascending v tie-break.
__global__ __launch_bounds__(256) void vq_mfma(
    const _Float16* __restrict__ z_hi, const _Float16* __restrict__ z_lo,
    const _Float16* __restrict__ e_hi, const _Float16* __restrict__ e_lo,
    const float* __restrict__ e_sq, unsigned long long* __restrict__ keys,
    int NQ, int VC, int vchunks, int vsub)
{
    const int t = threadIdx.x;
    const int lane = t & 63;
    const int w = t >> 6;
    const int qg = blockIdx.x / vchunks;
    const int vc = blockIdx.x % vchunks;
    const int vb0 = vc * (vsub * VC);

    __shared__ __align__(16) _Float16 eh_ls[256*32];
    __shared__ __align__(16) _Float16 el_ls[256*32];
    __shared__ float esq_ls[256];

    const int fr = lane & 15;
    const int kq = lane >> 4;
    const int qbase = qg*256 + w*64;
    f16x8 ah[4], al[4];
#pragma unroll
    for (int tq = 0; tq < 4; ++tq) {
        int q = qbase + tq*16 + fr;
        ah[tq] = *(const f16x8*)(z_hi + (size_t)q*32 + kq*8);
        al[tq] = *(const f16x8*)(z_lo + (size_t)q*32 + kq*8);
    }

    float bd[4][4]; int bv[4][4];
#pragma unroll
    for (int tq = 0; tq < 4; ++tq)
#pragma unroll
        for (int i = 0; i < 4; ++i) { bd[tq][i] = 3.4e38f; bv[tq][i] = 0; }

    for (int sub = 0; sub < vsub; ++sub) {
        const int vb = vb0 + sub * VC;
        {
            const float4* sH = (const float4*)(e_hi + (size_t)vb*32);
            const float4* sL = (const float4*)(e_lo + (size_t)vb*32);
            float4* dH = (float4*)eh_ls; float4* dL = (float4*)el_ls;
            int n4 = VC * 4;
            for (int x = t; x < n4; x += 256) {
                int row = x >> 2, c = x & 3;
                int ds = row*4 + (c ^ ((row >> 1) & 3));
                dH[ds] = sH[x]; dL[ds] = sL[x];
            }
            for (int v = t; v < VC; v += 256) esq_ls[v] = e_sq[vb + v];
        }
        __syncthreads();

        for (int vt = 0; vt < VC; vt += 16) {
            const int row = vt + fr;
            const int koff = (kq ^ ((row >> 1) & 3)) * 8;
            const f16x8 bh = *(const f16x8*)(eh_ls + (size_t)row*32 + koff);
            const f16x8 bl = *(const f16x8*)(el_ls + (size_t)row*32 + koff);
            float es = esq_ls[row];
            int vg = vb + row;
#pragma unroll
            for (int tq = 0; tq < 4; ++tq) {
                f32x4 acc = {es, es, es, es};
                acc = __builtin_amdgcn_mfma_f32_16x16x32_f16(ah[tq], bh, acc, 0,0,0);
                acc = __builtin_amdgcn_mfma_f32_16x16x32_f16(ah[tq], bl, acc, 0,0,0);
                acc = __builtin_amdgcn_mfma_f32_16x16x32_f16(al[tq], bh, acc, 0,0,0);
#pragma unroll
                for (int i = 0; i < 4; ++i)
                    if (acc[i] < bd[tq][i]) { bd[tq][i] = acc[i]; bv[tq][i] = vg; }
            }
        }
        __syncthreads();
    }

#pragma unroll
    for (int tq = 0; tq < 4; ++tq) {
#pragma unroll
        for (int i = 0; i < 4; ++i) {
            unsigned long long k = pack_key(bd[tq][i], bv[tq][i]);
#pragma unroll
            for (int m = 1; m < 16; m <<= 1) {
                unsigned long long o = __shfl_xor(k, m, 64); if (o < k) k = o;
            }
            if (fr == 0) atomicMin(&keys[qbase + tq*16 + kq*4 + i], k);
        }
    }
}

// ---------------------------------------------------------------- fused gather+upsample+phi+update+loss
// ROUND-25: r23-verified CHUNK=64 geometry (512 blocks; r24's CHUNK=16 quadrupled the
// per-block fixed costs -- w staging + barriers -- and regressed 43->81us) combined with
// r24's verified f_hat elimination (f_hat == f - f_rest invariant: df = -fr, lsum += fr^2;
// si5 writes f_hat = f - fr once; ~halves fuse HBM traffic).
// Gather staged via LDS (v0,v1,wg) + all-thread lerp; conv unroll 2 (r23-verified).
template<int CHUNK>
__global__ __launch_bounds__(256) void fuse_kernel(
    const float* __restrict__ f, const float* __restrict__ emb,
    const unsigned long long* __restrict__ keys,
    unsigned long long* __restrict__ keys_next, int nq_next,
    _Float16* __restrict__ zh_next, _Float16* __restrict__ zl_next, int s_next,
    const float* __restrict__ w, const float* __restrict__ bias,
    float* __restrict__ f_rest, float* __restrict__ f_hat,
    float* __restrict__ loss_acc, unsigned* __restrict__ done_ctr,
    float* __restrict__ out_loss, int pl, int from_f, int to_hat)
{
    constexpr int COLS = CHUNK + 2;
    constexpr int STR  = CHUNK + 4;
    constexpr int LPT  = CHUNK / 8;      // L-elements per thread
    const int t  = threadIdx.x;
    const int b  = blockIdx.y;
    const int l0 = blockIdx.x * CHUNK;

    if (keys_next) {
        int x = (b * gridDim.x + blockIdx.x) * 256 + t;
        if (x < nq_next) keys_next[x] = ~0ull;
    }

    __shared__ float w_s[3072];
    __shared__ float b_s[32];
    __shared__ float hs[32 * STR];
    __shared__ float red[4];
    __shared__ int   v0s[COLS], v1s[COLS];
    __shared__ float wgs[COLS];

    for (int x = t; x < 3072; x += 256) w_s[x] = w[x];
    if (t < 32) b_s[t] = bias[t];

    if (t < COLS) {
        int l = l0 - 1 + t;
        if (l < 0 || l >= LDIM) {
            v0s[t] = -1;
        } else {
            int lo, hi; float wg;
            if (pl == LDIM) { lo = l; hi = l; wg = 0.f; }
            else {
                float pos = (l + 0.5f) * ((float)pl / 1024.0f) - 0.5f;
                pos = fminf(fmaxf(pos, 0.f), (float)(pl - 1));
                lo = (int)floorf(pos);
                hi = min(lo + 1, pl - 1);
                wg = pos - (float)lo;
            }
            v0s[t] = (int)(keys[b * pl + lo] & 0xFFFFFFFFull);
            v1s[t] = (int)(keys[b * pl + hi] & 0xFFFFFFFFull);
            wgs[t] = wg;
        }
    }
    __syncthreads();

    // parallel gather: COLS x 8 quads over 256 threads
    for (int x = t; x < COLS * 8; x += 256) {
        int cx = x >> 3, i4 = x & 7;
        int v0 = v0s[cx];
        if (v0 < 0) {
            hs[(i4*4+0) * STR + cx] = 0.f;
            hs[(i4*4+1) * STR + cx] = 0.f;
            hs[(i4*4+2) * STR + cx] = 0.f;
            hs[(i4*4+3) * STR + cx] = 0.f;
        } else {
            float4 a = ((const float4*)(emb + (size_t)v0 * 32))[i4];
            float4 c = ((const float4*)(emb + (size_t)v1s[cx] * 32))[i4];
            float wg = wgs[cx], om = 1.0f - wg;
            hs[(i4*4+0) * STR + cx] = a.x * om + c.x * wg;
            hs[(i4*4+1) * STR + cx] = a.y * om + c.y * wg;
            hs[(i4*4+2) * STR + cx] = a.z * om + c.z * wg;
            hs[(i4*4+3) * STR + cx] = a.w * om + c.w * wg;
        }
    }
    __syncthreads();

    const int o  = t >> 3;
    const int lg = t & 7;
    const float* wrow = &w_s[o * 96];
    float acc[LPT];
#pragma unroll
    for (int u = 0; u < LPT; ++u) acc[u] = 0.f;
    const int hbase = lg * LPT;

#pragma unroll 2
    for (int i = 0; i < 32; ++i) {
        float w0 = wrow[i * 3 + 0], w1 = wrow[i * 3 + 1], w2 = wrow[i * 3 + 2];
        const float* hrow = &hs[i * STR + hbase];
        float hw[LPT + 2];
#pragma unroll
        for (int x = 0; x < LPT + 2; ++x) hw[x] = hrow[x];
#pragma unroll
        for (int u = 0; u < LPT; ++u) {
            acc[u] = fmaf(w0, hw[u], acc[u]);
            acc[u] = fmaf(w1, hw[u + 1], acc[u]);
            acc[u] = fmaf(w2, hw[u + 2], acc[u]);
        }
    }

    float lsum = 0.f;
    float frv[LPT];
    const int gbase = (b * 32 + o) * LDIM + l0 + lg * LPT;
#pragma unroll
    for (int u = 0; u < LPT; ++u) {
        float hval = hs[o * STR + lg * LPT + 1 + u];
        float y = acc[u] + b_s[o];
        float ph = 0.5f * hval + 0.5f * y;
        int gi = gbase + u;
        float fr = (from_f ? f[gi] : f_rest[gi]) - ph;
        if (to_hat) f_hat[gi] = f[gi] - fr;
        else        f_rest[gi] = fr;
        frv[u] = fr;
        lsum = fmaf(fr, fr, lsum);      // df = fh - f = -fr
    }

    if (zh_next) {
        __syncthreads();
#pragma unroll
        for (int u = 0; u < LPT; ++u) hs[o * STR + lg * LPT + u] = frv[u];
        __syncthreads();
        int npos = CHUNK / s_next;
        int qn_base = b * (LDIM / s_next) + l0 / s_next;
        for (int v = t; v < npos * 32; v += 256) {
            int jl = v >> 5, c = v & 31;
            float zv;
            if (s_next == 1) zv = hs[c * STR + jl];
            else {
                int cl = jl * s_next + (s_next >> 1) - 1;
                zv = 0.5f * (hs[c * STR + cl] + hs[c * STR + cl + 1]);
            }
            _Float16 h = (_Float16)zv;
            float r = zv - (float)h;
            size_t zi = (size_t)(qn_base + jl) * 32 + c;
            zh_next[zi] = h;
            zl_next[zi] = (_Float16)r;
        }
    }

#pragma unroll
    for (int off = 32; off > 0; off >>= 1) lsum += __shfl_down(lsum, off, 64);
    if ((t & 63) == 0) red[t >> 6] = lsum;
    __syncthreads();
    if (t == 0) {
        atomicAdd(loss_acc, red[0] + red[1] + red[2] + red[3]);
        if (out_loss) {
            __threadfence();
            unsigned old = atomicAdd(done_ctr, 1u);
            if (old == (unsigned)(gridDim.x * gridDim.y - 1)) {
                float lv = atomicAdd(loss_acc, 0.0f);
                *out_loss = lv * (1.25f / (6.0f * (float)BCL));
            }
        }
    }
}

// ---------------------------------------------------------------- launch
extern "C" void kernel_launch(void* const* d_in, const int* in_sizes, int n_in,
                              void* d_out, int out_size, void* d_ws, size_t ws_size,
                              hipStream_t stream)
{
    const float* f    = (const float*)d_in[0];
    const float* emb  = (const float*)d_in[1];
    const float* phiw = (const float*)d_in[2];
    const float* phib = (const float*)d_in[3];

    float* f_hat    = (float*)d_out;
    float* out_loss = f_hat + BCL;

    const int pls[6]   = {1, 4, 16, 64, 256, 1024};
    const int lpls[6]  = {0, 2, 4, 6, 8, 10};
    const int vchm[6]  = {0, 0, 64, 16, 8, 4};
    const int vsbm[6]  = {0, 0, 1, 1, 2, 4};
    const int pidx[6]  = {0, 0, 1, 2, 3, 3};
    const int snx[6]   = {256, 64, 16, 4, 1, 0};

    char* ws = (char*)d_ws;
    float* f_rest = (float*)ws;

    size_t base = (size_t)BCL * 4;
    size_t off = base;
    unsigned long long* keysA = (unsigned long long*)(ws + off);
    unsigned long long* keysB = keysA + 32768;
    off += (size_t)65536 * 8;
    _Float16* z_hi = (_Float16*)(ws + off); off += (size_t)32768 * 32 * 2;
    _Float16* z_lo = (_Float16*)(ws + off); off += (size_t)32768 * 32 * 2;
    _Float16* e_hi = (_Float16*)(ws + off); off += (size_t)VDIM * 32 * 2;
    _Float16* e_lo = (_Float16*)(ws + off); off += (size_t)VDIM * 32 * 2;
    size_t need_mf = off + (size_t)VDIM * 4 + 64;
    bool mf = ws_size >= need_mf;

    if (mf) {
        float* e_sq        = (float*)(ws + off);
        float* loss_acc    = e_sq + VDIM;
        unsigned* done_ctr = (unsigned*)(loss_acc + 1);

        for (int si = 0; si < 6; ++si) {
            int pl = pls[si], s = LDIM / pl, NQ = BDIM * pl;
            unsigned long long* k  = (si & 1) ? keysB : keysA;
            unsigned long long* kn = (si >= 1 && si < 5) ? ((si & 1) ? keysA : keysB) : nullptr;
            int nq_next = (si < 5) ? BDIM * pls[si + 1] : 0;

            if (si <= 1) {
                int grid = NQ + (si == 0 ? 16 : 0);
                vq_small<<<dim3(grid), 256, 0, stream>>>(
                    (si == 0) ? f : f_rest, emb, e_hi, e_lo, e_sq, k,
                    loss_acc, done_ctr, lpls[si], s, NQ);
            } else {
                int vcm = vchm[si], vsb = vsbm[si];
                int VC = VDIM / (vcm * vsb);
                vq_mfma<<<dim3((NQ / 256) * vcm), 256, 0, stream>>>(
                    z_hi, z_lo, e_hi, e_lo, e_sq, k, NQ, VC, vcm, vsb);
            }

            bool zw = (si >= 1 && si <= 4);
            _Float16* zh = zw ? z_hi : nullptr;
            _Float16* zl = zw ? z_lo : nullptr;
            const float* wsi = phiw + (size_t)pidx[si] * 3072;
            const float* bsi = phib + (size_t)pidx[si] * 32;
            int from_f = (si == 0) ? 1 : 0;
            int to_hat = (si == 5) ? 1 : 0;
            float* ol = (si == 5) ? out_loss : nullptr;

            fuse_kernel<64><<<dim3(16, 32), 256, 0, stream>>>(
                f, emb, k, kn, nq_next, zh, zl, snx[si], wsi, bsi,
                f_rest, f_hat, loss_acc, done_ctr, ol, pl, from_f, to_hat);
        }
        return;
    }

    // ---- small-ws fallback: scan pipeline (correctness-first, same fuse semantics)
    {
        off = base;
        size_t need_pp = base + (size_t)65536 * 8 + (size_t)VDIM * 4 + 64;
        bool pp = ws_size >= need_pp;
        keysB = pp ? keysA + 32768 : keysA;
        off += pp ? (size_t)65536 * 8 : (size_t)32768 * 8;
        float* e_sq        = (float*)(ws + off);
        float* loss_acc    = e_sq + VDIM;
        unsigned* done_ctr = (unsigned*)(loss_acc + 1);

        init_kernel<<<dim3((BCL + 255) / 256), 256, 0, stream>>>(
            f, emb, f_rest, e_sq, loss_acc, done_ctr, keysA, 32768);

        for (int si = 0; si < 6; ++si) {
            int pl = pls[si], s = LDIM / pl, NQ = BDIM * pl;
            unsigned long long* k  = (si & 1) ? keysB : keysA;
            unsigned long long* kn = (si < 5 && pp) ? ((si & 1) ? keysA : keysB) : nullptr;
            int nq_next = (si < 5) ? BDIM * pls[si + 1] : 0;
            if (!pp && si > 0) hipMemsetAsync(k, 0xFF, (size_t)NQ * 8, stream);
            vq_small<<<dim3(NQ), 256, 0, stream>>>(
                (si == 0) ? f : f_rest, emb, nullptr, nullptr, e_sq, k,
                loss_acc, done_ctr, lpls[si], s, NQ);
            fuse_kernel<64><<<dim3(16, 32), 256, 0, stream>>>(
                f, emb, k, kn, nq_next, nullptr, nullptr, snx[si],
                phiw + (size_t)pidx[si] * 3072, phib + (size_t)pidx[si] * 32,
                f_rest, f_hat, loss_acc, done_ctr,
                (si == 5) ? out_loss : nullptr, pl, (si == 0) ? 1 : 0, (si == 5) ? 1 : 0);
        }
    }
}